// Round 10
// baseline (199.416 us; speedup 1.0000x reference)
//
#include <hip/hip_runtime.h>

// Problem constants (match reference)
#define B 32
#define S 32
#define N 128
#define U 64
#define E 2
#define NCLS 5

// R17: ALL weights (Wmsg+Wg+Ug = 128KB) LDS-staged at the proven 16-wave/CU
// shape. R15/R16: TLP lever saturated at ~19.5us/step. Port accounting: the
// weight stream thrashes L1 (working set 128KB vs 32KB L1) -> every weight
// load is an L2 trip AND h[b] is evicted. Fix: 1024-thr blocks, 1 block/CU
// (grid 256), LDS 152KB: weights 128KB + 24KB alias-rotated reduce scratch.
// Weight serving moves to the 256B/cyc DS pipe (~1.7us/step); L1 then holds
// exactly h[b]=32KB -> h-broadcast reads become L1 hits. Split-K=2 per row
// pair (8 groups x 2 halves = 16 waves), R15's exact FMA/reduce order ->
// bit-identical output. R12's earlier LDS-null was at 8 waves (latency-bound,
// h still evicted); this is the port-bound regime where it should pay.

__device__ __forceinline__ float sigmoid_f(float x) {
    return __fdividef(1.f, 1.f + __expf(-x));
}
__device__ __forceinline__ float tanh_f(float x) {
    float t = __expf(-2.f * fabsf(x));
    float y = __fdividef(1.f - t, 1.f + t);
    return copysignf(y, x);
}
// broadcast lane u's value of v to all lanes (VALU pipe, no LDS)
__device__ __forceinline__ float bcast(float v, int u) {
    return __uint_as_float(__builtin_amdgcn_readlane(__float_as_uint(v), u));
}

template <int FIRST, int LAST>
__global__ __launch_bounds__(1024, 4) void k_step(
    const float* __restrict__ x, const int* __restrict__ lens,
    const float* __restrict__ hin, float* __restrict__ hout,
    const float* __restrict__ A, const float* __restrict__ Wmsg,
    const float* __restrict__ bmsg, const float* __restrict__ Wg,
    const float* __restrict__ Ug, const float* __restrict__ bg,
    const float* __restrict__ fcw, float* __restrict__ partial, int l) {
    __shared__ float wms[E * U * U];          // 32 KB
    __shared__ float wgs[3 * U * U];          // 48 KB
    __shared__ float ugs[3 * U * U];          // 48 KB
    __shared__ float sA[8][2][2][2][64];      // 16 KB (sred / gate-zr / c2)
    __shared__ float sB[8][2][2][64];         //  8 KB (avred / gate-c / red)
    int tid = threadIdx.x;
    int wave = tid >> 6, lane = tid & 63;
    int g = wave & 7;        // row group (2 rows each): 8 groups = 16 rows
    int k = wave >> 3;       // split half: 0 or 1
    int b = blockIdx.x >> 3;
    int j = blockIdx.x & 7;  // 8 blocks per batch
    int n0 = __builtin_amdgcn_readfirstlane(j * 16 + g * 2);
    int u0 = __builtin_amdgcn_readfirstlane(k * 32);   // this wave's u-range
    int m0 = __builtin_amdgcn_readfirstlane(k * 64);   // this wave's m-range

    // ---- stage ALL weights for layer l into LDS (8 float4 per thread)
    {
        const float4* m4 = (const float4*)(Wmsg + (size_t)l * E * U * U);
        float4* md = (float4*)wms;
#pragma unroll
        for (int i = 0; i < 2; ++i) md[tid + i * 1024] = m4[tid + i * 1024];
        const float4* g4 = (const float4*)(Wg + (size_t)l * 3 * U * U);
        float4* gd = (float4*)wgs;
#pragma unroll
        for (int i = 0; i < 3; ++i) gd[tid + i * 1024] = g4[tid + i * 1024];
        const float4* u4 = (const float4*)(Ug + (size_t)l * 3 * U * U);
        float4* ud = (float4*)ugs;
#pragma unroll
        for (int i = 0; i < 3; ++i) ud[tid + i * 1024] = u4[tid + i * 1024];
    }
    // no explicit sync needed: first LDS weight read is after sync1 below

    const float* __restrict__ hsrc;
    if (FIRST) {
        int idx = lens[b] - 1;
        idx = idx < 0 ? 0 : (idx > S - 1 ? S - 1 : idx);
        hsrc = x + (size_t)(b * S + idx) * N * U;
    } else {
        hsrc = hin + (size_t)b * N * U;
    }

    float hv0 = hsrc[(n0 + 0) * U + lane];
    float hv1 = hsrc[(n0 + 1) * U + lane];

    // ---- P1: aggregate partials over this wave's m-half (64 m's)
    float s00 = 0.f, s01 = 0.f, s10 = 0.f, s11 = 0.f;  // [row][edge]
    {
        const float4* A00 = (const float4*)(A + (((size_t)b * E + 0) * N + n0 + 0) * N + m0);
        const float4* A10 = (const float4*)(A + (((size_t)b * E + 0) * N + n0 + 1) * N + m0);
        const float4* A01 = (const float4*)(A + (((size_t)b * E + 1) * N + n0 + 0) * N + m0);
        const float4* A11 = (const float4*)(A + (((size_t)b * E + 1) * N + n0 + 1) * N + m0);
#pragma unroll 8
        for (int m4 = 0; m4 < 16; ++m4) {
            float4 a00 = A00[m4], a10 = A10[m4], a01 = A01[m4], a11 = A11[m4];
            float q0 = hsrc[(m0 + m4 * 4 + 0) * U + lane];
            float q1 = hsrc[(m0 + m4 * 4 + 1) * U + lane];
            float q2 = hsrc[(m0 + m4 * 4 + 2) * U + lane];
            float q3 = hsrc[(m0 + m4 * 4 + 3) * U + lane];
            s00 = fmaf(a00.x, q0, s00); s00 = fmaf(a00.y, q1, s00);
            s00 = fmaf(a00.z, q2, s00); s00 = fmaf(a00.w, q3, s00);
            s10 = fmaf(a10.x, q0, s10); s10 = fmaf(a10.y, q1, s10);
            s10 = fmaf(a10.z, q2, s10); s10 = fmaf(a10.w, q3, s10);
            s01 = fmaf(a01.x, q0, s01); s01 = fmaf(a01.y, q1, s01);
            s01 = fmaf(a01.z, q2, s01); s01 = fmaf(a01.w, q3, s01);
            s11 = fmaf(a11.x, q0, s11); s11 = fmaf(a11.y, q1, s11);
            s11 = fmaf(a11.z, q2, s11); s11 = fmaf(a11.w, q3, s11);
        }
    }
    sA[g][k][0][0][lane] = s00;
    sA[g][k][0][1][lane] = s01;
    sA[g][k][1][0][lane] = s10;
    sA[g][k][1][1][lane] = s11;
    __syncthreads();  // sync1 (also covers weight staging)
    s00 = sA[g][0][0][0][lane] + sA[g][1][0][0][lane];
    s01 = sA[g][0][0][1][lane] + sA[g][1][0][1][lane];
    s10 = sA[g][0][1][0][lane] + sA[g][1][1][0][lane];
    s11 = sA[g][0][1][1][lane] + sA[g][1][1][1][lane];

    // ---- P2: msg partials over this wave's u-half (LDS weights)
    float av0, av1;
    {
        float bm = (k == 0) ? bmsg[l * U + lane] : 0.f;
        av0 = bm; av1 = bm;
        const float* W0 = wms + lane;
        const float* W1 = wms + U * U + lane;
#pragma unroll 16
        for (int uu = 0; uu < 32; ++uu) {
            int u = u0 + uu;
            float w = W0[u * U];
            av0 = fmaf(bcast(s00, u), w, av0);
            av1 = fmaf(bcast(s10, u), w, av1);
        }
#pragma unroll 16
        for (int uu = 0; uu < 32; ++uu) {
            int u = u0 + uu;
            float w = W1[u * U];
            av0 = fmaf(bcast(s01, u), w, av0);
            av1 = fmaf(bcast(s11, u), w, av1);
        }
    }
    sB[g][k][0][lane] = av0;
    sB[g][k][1][lane] = av1;
    __syncthreads();  // sync2
    av0 = sB[g][0][0][lane] + sB[g][1][0][lane];
    av1 = sB[g][0][1][lane] + sB[g][1][1][lane];

    // ---- P3: gate matmul partials over this wave's u-half (LDS weights)
    const float* Wg0 = wgs + lane;
    const float* Wg1 = wgs + U * U + lane;
    const float* Wg2 = wgs + 2 * U * U + lane;
    const float* Ug0 = ugs + lane;
    const float* Ug1 = ugs + U * U + lane;
    const float* Ug2 = ugs + 2 * U * U + lane;
    float accz0, accz1, accr0, accr1, accc0, accc1;
    {
        float bz = (k == 0) ? bg[(l * 3 + 0) * U + lane] : 0.f;
        float br = (k == 0) ? bg[(l * 3 + 1) * U + lane] : 0.f;
        float bcc = (k == 0) ? bg[(l * 3 + 2) * U + lane] : 0.f;
        accz0 = bz; accz1 = bz;
        accr0 = br; accr1 = br;
        accc0 = bcc; accc1 = bcc;
#pragma unroll 8
        for (int uu = 0; uu < 32; ++uu) {
            int u = u0 + uu;
            float w0 = Wg0[u * U], w1 = Wg1[u * U], w2 = Wg2[u * U];
            float g0 = Ug0[u * U], g1 = Ug1[u * U];
            float a0 = bcast(av0, u), a1 = bcast(av1, u);
            float h0 = bcast(hv0, u), h1 = bcast(hv1, u);
            accz0 = fmaf(a0, w0, accz0); accz0 = fmaf(h0, g0, accz0);
            accz1 = fmaf(a1, w0, accz1); accz1 = fmaf(h1, g0, accz1);
            accr0 = fmaf(a0, w1, accr0); accr0 = fmaf(h0, g1, accr0);
            accr1 = fmaf(a1, w1, accr1); accr1 = fmaf(h1, g1, accr1);
            accc0 = fmaf(a0, w2, accc0);
            accc1 = fmaf(a1, w2, accc1);
        }
    }
    // z,r partials -> A (A reads of P1 completed before sync2)
    sA[g][k][0][0][lane] = accz0;
    sA[g][k][0][1][lane] = accz1;
    sA[g][k][1][0][lane] = accr0;
    sA[g][k][1][1][lane] = accr1;
    __syncthreads();  // sync3
    accz0 = sA[g][0][0][0][lane] + sA[g][1][0][0][lane];
    accz1 = sA[g][0][0][1][lane] + sA[g][1][0][1][lane];
    accr0 = sA[g][0][1][0][lane] + sA[g][1][1][0][lane];
    accr1 = sA[g][0][1][1][lane] + sA[g][1][1][1][lane];
    // c partials -> B (B reads of P2 completed before sync3)
    sB[g][k][0][lane] = accc0;
    sB[g][k][1][lane] = accc1;
    __syncthreads();  // sync4
    accc0 = sB[g][0][0][lane] + sB[g][1][0][lane];
    accc1 = sB[g][0][1][lane] + sB[g][1][1][lane];

    // ---- P5: rh matmul partials over this wave's u-half
    float rh0 = sigmoid_f(accr0) * hv0;
    float rh1 = sigmoid_f(accr1) * hv1;
    float c20 = 0.f, c21 = 0.f;
#pragma unroll 16
    for (int uu = 0; uu < 32; ++uu) {
        int u = u0 + uu;
        float g2 = Ug2[u * U];
        c20 = fmaf(bcast(rh0, u), g2, c20);
        c21 = fmaf(bcast(rh1, u), g2, c21);
    }
    sA[g][k][0][0][lane] = c20;  // A reads of P3 completed before sync4
    sA[g][k][0][1][lane] = c21;
    __syncthreads();  // sync5
    accc0 += sA[g][0][0][0][lane] + sA[g][1][0][0][lane];
    accc1 += sA[g][0][0][1][lane] + sA[g][1][0][1][lane];

    float zg0 = sigmoid_f(accz0), zg1 = sigmoid_f(accz1);
    float hn0 = (1.f - zg0) * hv0 + zg0 * tanh_f(accc0);
    float hn1 = (1.f - zg1) * hv1 + zg1 * tanh_f(accc1);

    if (!LAST) {
        if (k == 0) {
            hout[((size_t)b * N + n0 + 0) * U + lane] = hn0;
            hout[((size_t)b * N + n0 + 1) * U + lane] = hn1;
        }
    } else {
        // classification partial: k==0 waves own their 2 rows
        float* red = &sB[0][0][0][0];  // alias B (B reads done before sync5)
        if (k == 0) {
            float lg0[NCLS], lg1[NCLS];
            float rv0 = hn0 > 0.f ? hn0 : 0.f;
            float rv1 = hn1 > 0.f ? hn1 : 0.f;
#pragma unroll
            for (int c = 0; c < NCLS; c++) {
                float w = fcw[lane * NCLS + c];
                lg0[c] = rv0 * w;
                lg1[c] = rv1 * w;
            }
#pragma unroll
            for (int off = 32; off; off >>= 1) {
#pragma unroll
                for (int c = 0; c < NCLS; c++) {
                    lg0[c] += __shfl_xor(lg0[c], off, 64);
                    lg1[c] += __shfl_xor(lg1[c], off, 64);
                }
            }
            if (lane == 0) {
#pragma unroll
                for (int c = 0; c < NCLS; c++)
                    red[g * NCLS + c] = fmaxf(lg0[c], lg1[c]);
            }
        }
        __syncthreads();
        if (tid < NCLS) {
            float m = red[tid];
            for (int w = 1; w < 8; ++w) m = fmaxf(m, red[w * NCLS + tid]);
            partial[(size_t)(b * 8 + j) * NCLS + tid] = m;
        }
    }
}

// ---------------------------------------------------------------------------
// k_final: out[b][c] = max over 8 block-partials + fc_b
__global__ void k_final(const float* __restrict__ partial, const float* __restrict__ fcb,
                        float* __restrict__ out) {
    int b = blockIdx.x, c = threadIdx.x;
    if (c < NCLS) {
        float m = -3.4e38f;
        for (int jj = 0; jj < 8; ++jj)
            m = fmaxf(m, partial[(size_t)(b * 8 + jj) * NCLS + c]);
        out[b * NCLS + c] = m + fcb[c];
    }
}

// ---------------------------------------------------------------------------
extern "C" void kernel_launch(void* const* d_in, const int* in_sizes, int n_in,
                              void* d_out, int out_size, void* d_ws, size_t ws_size,
                              hipStream_t stream) {
    const float* x    = (const float*)d_in[0];
    const int*   lens = (const int*)d_in[1];
    const float* A    = (const float*)d_in[2];
    const float* Wmsg = (const float*)d_in[3];
    const float* bmsg = (const float*)d_in[4];
    const float* Wg   = (const float*)d_in[5];
    const float* Ug   = (const float*)d_in[6];
    const float* bg   = (const float*)d_in[7];
    const float* fcw  = (const float*)d_in[8];
    const float* fcb  = (const float*)d_in[9];
    float* out = (float*)d_out;

    float* hA      = (float*)d_ws;                   // [B][N][U]
    float* hB      = hA + (size_t)B * N * U;         // [B][N][U]
    float* partial = hB + (size_t)B * N * U;         // [B][8][NCLS]

    // steps 0-2: layer 0; steps 3-5: layer 1
    k_step<1, 0><<<B * 8, 1024, 0, stream>>>(x, lens, nullptr, hA, A, Wmsg, bmsg, Wg, Ug, bg, fcw, partial, 0);
    k_step<0, 0><<<B * 8, 1024, 0, stream>>>(x, lens, hA, hB, A, Wmsg, bmsg, Wg, Ug, bg, fcw, partial, 0);
    k_step<0, 0><<<B * 8, 1024, 0, stream>>>(x, lens, hB, hA, A, Wmsg, bmsg, Wg, Ug, bg, fcw, partial, 0);
    k_step<0, 0><<<B * 8, 1024, 0, stream>>>(x, lens, hA, hB, A, Wmsg, bmsg, Wg, Ug, bg, fcw, partial, 1);
    k_step<0, 0><<<B * 8, 1024, 0, stream>>>(x, lens, hB, hA, A, Wmsg, bmsg, Wg, Ug, bg, fcw, partial, 1);
    k_step<0, 1><<<B * 8, 1024, 0, stream>>>(x, lens, hA, hB, A, Wmsg, bmsg, Wg, Ug, bg, fcw, partial, 1);
    k_final<<<B, 64, 0, stream>>>(partial, fcb, out);
}